// Round 7
// baseline (313.476 us; speedup 1.0000x reference)
//
#include <hip/hip_runtime.h>

// Problem constants (from reference): B=1024, D=128, N_LANGS=8000
#define NB    1024
#define ND    128
#define NF4   32
#define NLANG 8000

#define TILE    64
#define NGRP    16
#define GSTRIDE 129
#define NBLK    256

// Accumulate per-component |x - y| into A. Plain function (no multi-line
// macro: backslash continuations were mangled in transit last round).
__device__ __forceinline__ void acc4(float4& A, const float4 X, const float4 Y) {
    A.x += __builtin_fabsf(X.x - Y.x);
    A.y += __builtin_fabsf(X.y - Y.y);
    A.z += __builtin_fabsf(X.z - Y.z);
    A.w += __builtin_fabsf(X.w - Y.w);
}

__global__ __launch_bounds__(256) void lesl_main(
    const int*   __restrict__ ids,
    const float* __restrict__ emb,
    const float* __restrict__ md,
    float*       __restrict__ partials)   // [NBLK] float2: (sum, count)
{
    // row r lives at f4 offset (r>>2)*GSTRIDE + (r&3)*32 + c
    // GSTRIDE=129 f4 -> group g starts at bank 4g: sJ reads 2-way (free), sI broadcast
    __shared__ float4 sI[NGRP * GSTRIDE];
    __shared__ float4 sJ[NGRP * GSTRIDE];
    __shared__ float  red[8];

    const int tid = threadIdx.x;
    const int bi  = blockIdx.x & 15;
    const int bj  = blockIdx.x >> 4;
    const int i0  = bi * TILE;
    const int j0  = bj * TILE;

    const int tx = tid & 15;   // j group (4 rows)
    const int ty = tid >> 4;   // i group (4 rows)

    // HOIST: ids then md gathers issued first; ~900cy HBM latency hides
    // under staging + the 32-iter compute loop.
    int iid[4], jid[4];
    #pragma unroll
    for (int w = 0; w < 4; ++w) {
        iid[w] = ids[i0 + (ty << 2) + w];
        jid[w] = ids[j0 + (tx << 2) + w];
    }
    float mdv[4][4];
    #pragma unroll
    for (int a = 0; a < 4; ++a) {
        #pragma unroll
        for (int b = 0; b < 4; ++b) {
            mdv[a][b] = md[(size_t)iid[a] * NLANG + jid[b]];
        }
    }

    // Cooperative stage: 64 rows x 32 f4 per tile, 8 f4/thread/tile
    const float4* embv = (const float4*)emb;
    for (int k = tid; k < TILE * NF4; k += 256) {
        const int r   = k >> 5;
        const int c   = k & 31;
        const int dst = (r >> 2) * GSTRIDE + ((r & 3) << 5) + c;
        sI[dst] = embv[(size_t)(i0 + r) * NF4 + c];
        sJ[dst] = embv[(size_t)(j0 + r) * NF4 + c];
    }
    __syncthreads();

    const float4* pI = &sI[ty * GSTRIDE];
    const float4* pJ = &sJ[tx * GSTRIDE];

    float4 acc[4][4];
    #pragma unroll
    for (int a = 0; a < 4; ++a) {
        #pragma unroll
        for (int b = 0; b < 4; ++b) {
            acc[a][b] = make_float4(0.f, 0.f, 0.f, 0.f);
        }
    }

    #pragma unroll 4
    for (int c = 0; c < 32; ++c) {
        float4 x[4], y[4];
        #pragma unroll
        for (int w = 0; w < 4; ++w) {
            x[w] = pI[(w << 5) + c];
            y[w] = pJ[(w << 5) + c];
        }
        #pragma unroll
        for (int a = 0; a < 4; ++a) {
            #pragma unroll
            for (int b = 0; b < 4; ++b) {
                acc4(acc[a][b], x[a], y[b]);
            }
        }
    }

    float s = 0.0f, cnt = 0.0f;
    #pragma unroll
    for (int a = 0; a < 4; ++a) {
        #pragma unroll
        for (int b = 0; b < 4; ++b) {
            const float4 A = acc[a][b];
            const float sad  = (A.x + A.y) + (A.z + A.w);
            const float diff = __builtin_fabsf(sad * 0.0078125f - mdv[a][b]); // /128 exact
            if (iid[a] != jid[b]) { s += diff; cnt += 1.0f; }
        }
    }

    // wave64 shuffle reduce, 4-wave LDS reduce, one store/block
    #pragma unroll
    for (int off = 32; off > 0; off >>= 1) {
        s   += __shfl_down(s,   off, 64);
        cnt += __shfl_down(cnt, off, 64);
    }
    const int wid = tid >> 6;
    if ((tid & 63) == 0) { red[wid] = s; red[4 + wid] = cnt; }
    __syncthreads();
    if (tid == 0) {
        const float S = red[0] + red[1] + red[2] + red[3];
        const float C = red[4] + red[5] + red[6] + red[7];
        ((float2*)partials)[blockIdx.x] = make_float2(S, C);
    }
}

// Reduce NBLK (sum,count) pairs -> out[0] = S/C. One block.
__global__ __launch_bounds__(256) void lesl_reduce(
    const float* __restrict__ partials, float* __restrict__ out)
{
    __shared__ float red[8];
    const int tid = threadIdx.x;
    const float2 v = ((const float2*)partials)[tid];   // NBLK == 256

    float s = v.x, c = v.y;
    #pragma unroll
    for (int off = 32; off > 0; off >>= 1) {
        s += __shfl_down(s, off, 64);
        c += __shfl_down(c, off, 64);
    }
    const int wid = tid >> 6;
    if ((tid & 63) == 0) { red[wid] = s; red[4 + wid] = c; }
    __syncthreads();
    if (tid == 0) {
        const float S = red[0] + red[1] + red[2] + red[3];
        const float C = red[4] + red[5] + red[6] + red[7];
        out[0] = S / C;
    }
}

extern "C" void kernel_launch(void* const* d_in, const int* in_sizes, int n_in,
                              void* d_out, int out_size, void* d_ws, size_t ws_size,
                              hipStream_t stream) {
    const int*   ids = (const int*)d_in[0];
    const float* emb = (const float*)d_in[1];
    const float* md  = (const float*)d_in[2];
    float* out = (float*)d_out;
    float* ws  = (float*)d_ws;   // float2[NBLK] partials (poison overwritten before read)

    lesl_main<<<dim3(NBLK), dim3(256), 0, stream>>>(ids, emb, md, ws);
    lesl_reduce<<<dim3(1), dim3(256), 0, stream>>>(ws, out);
}